// Round 6
// baseline (278.624 us; speedup 1.0000x reference)
//
#include <hip/hip_runtime.h>

#define T_LEN  16384
#define LTAG   64
#define F_PER  14
#define CHUNK  16
#define NCHUNK (T_LEN / CHUNK)   // 1024 -> measured optimum (R3: 226us total)
#define BOS_ID 0
#define EOS_ID 1
#define NREG   6
#define REGSZ  833334      // 6 x 833334 >= 5,000,000 ; 3.33 MB/region -> L2-resident (proven)
#define WARM   48          // forward warm-up (proven)
#define WB     96          // backward warm-up for bp backtrack coalescence
#define EQ     (T_LEN * LTAG / 4)   // emissions quarter: 262144 elements

typedef __attribute__((ext_vector_type(4))) int i4;

// workspace layout (bytes)
static constexpr size_t EM_OFF = 0;                                 // float[T*64] 4 MB
static constexpr size_t BP_OFF = EM_OFF + (size_t)T_LEN * 64 * 4;   // uchar[T*64] 1 MB
static constexpr size_t AE_OFF = BP_OFF + (size_t)T_LEN * 64;       // float[64]
static constexpr size_t PS_OFF = AE_OFF + 512;                      // double[1024]

// ---------------------------------------------------------------------------
// K1: emissions  em[t,l] = sum_f w[feat[t,l,f]]  (fp32)
// At its structural floor (~88us total): 56M random 4B gathers / 256 CUs at
// ~1 L2-request/cyc/CU. NREG=6 keeps regions L2-resident (measured optimum:
// NREG=10 108us, 6 88us, 3 118us). Launched as 4 quarter-grids (pointer
// offset only, same total work): anything >=23us now surfaces in the top-5
// profile table -- instrumentation for phase3/backtrack, which have never
// been visible behind the single 88us emissions dispatch.
// ---------------------------------------------------------------------------
__global__ __launch_bounds__(256) void k_emissions(
    const int* __restrict__ idx, const float* __restrict__ w, float* __restrict__ em)
{
    __shared__ int sIdx[256 * F_PER];          // 14 KB
    const int tid = threadIdx.x;
    const int* g = idx + (size_t)blockIdx.x * (256 * F_PER);
    for (int x = tid * 4; x < 256 * F_PER; x += 1024)
        *(i4*)(sIdx + x) = __builtin_nontemporal_load((const i4*)(g + x));
    __syncthreads();
    int id[F_PER];
#pragma unroll
    for (int f = 0; f < F_PER; ++f) id[f] = sIdx[tid * F_PER + f];
    float sf[F_PER];
#pragma unroll
    for (int f = 0; f < F_PER; ++f) sf[f] = 0.f;
    for (int r = 0; r < NREG; ++r) {
        const int lo = r * REGSZ;
#pragma unroll
        for (int f = 0; f < F_PER; ++f)
            if ((unsigned)(id[f] - lo) < (unsigned)REGSZ) sf[f] += w[id[f]];
    }
    float s = 0.f;
#pragma unroll
    for (int f = 0; f < F_PER; f += 2) s += sf[f] + sf[f + 1];
    em[(size_t)blockIdx.x * 256 + tid] = s;
}

// ---------------------------------------------------------------------------
// K2: forward Viterbi with self-warm. EXACT R3 structure (the measured
// optimum) + 4-deep em prefetch queue (the one R4/R5 change with positive
// per-step evidence; covers ~2000cy of cross-XCD em L2-miss latency).
// ---------------------------------------------------------------------------
__global__ __launch_bounds__(64, 1) void k_phase3(
    const float* __restrict__ trans, const float* __restrict__ em,
    unsigned char* __restrict__ bp, float* __restrict__ aEnd)
{
    __shared__ __align__(16) float sa[64];
    const int c = blockIdx.x;
    const int tid = threadIdx.x;                 // = state j
    const int t0 = c * CHUNK;
    int nsteps = (T_LEN - 1) - t0; if (nsteps > CHUNK) nsteps = CHUNK;

    float tr_[64];                               // T[i][tid], i = 0..63
#pragma unroll
    for (int i = 0; i < 64; ++i) tr_[i] = trans[i * 64 + tid];

    float a; int tw;
    if (t0 <= WARM) { tw = 0; a = tr_[BOS_ID] + em[tid]; }   // exact init at t=0
    else            { tw = t0 - WARM; a = em[(size_t)tw * 64 + tid]; } // neutral init

    // 4-deep emission prefetch queue (static indexing -> stays in VGPRs)
    #define EMROW(t) em[(size_t)((t) < T_LEN - 1 ? (t) : T_LEN - 1) * 64 + tid]
    float p0 = EMROW(tw + 1), p1 = EMROW(tw + 2), p2 = EMROW(tw + 3), p3 = EMROW(tw + 4);
    const float4* ap = (const float4*)sa;

    // warm (or exact-replay) steps: no backpointers
    for (int t = tw + 1; t <= t0; ++t) {
        const float e = p0;
        p0 = p1; p1 = p2; p2 = p3; p3 = EMROW(t + 4);
        sa[tid] = a;
        float m = -3.0e38f;
#pragma unroll
        for (int g = 0; g < 4; ++g) {
            const float4 v0 = ap[4*g+0], v1 = ap[4*g+1], v2 = ap[4*g+2], v3 = ap[4*g+3];
            float s0[16];
            s0[0]  = tr_[16*g+0]  + v0.x;  s0[1]  = tr_[16*g+1]  + v0.y;
            s0[2]  = tr_[16*g+2]  + v0.z;  s0[3]  = tr_[16*g+3]  + v0.w;
            s0[4]  = tr_[16*g+4]  + v1.x;  s0[5]  = tr_[16*g+5]  + v1.y;
            s0[6]  = tr_[16*g+6]  + v1.z;  s0[7]  = tr_[16*g+7]  + v1.w;
            s0[8]  = tr_[16*g+8]  + v2.x;  s0[9]  = tr_[16*g+9]  + v2.y;
            s0[10] = tr_[16*g+10] + v2.z;  s0[11] = tr_[16*g+11] + v2.w;
            s0[12] = tr_[16*g+12] + v3.x;  s0[13] = tr_[16*g+13] + v3.y;
            s0[14] = tr_[16*g+14] + v3.z;  s0[15] = tr_[16*g+15] + v3.w;
#pragma unroll
            for (int st = 8; st >= 1; st >>= 1)
#pragma unroll
                for (int i = 0; i < st; ++i) s0[i] = fmaxf(s0[i], s0[i + st]);
            m = fmaxf(m, s0[0]);
        }
        a = e + m;
    }

    // real steps: emit backpointers (first-max semantics = jnp.argmax)
    const int tend = t0 + nsteps;
    for (int t = t0 + 1; t <= tend; ++t) {
        const float e = p0;
        p0 = p1; p1 = p2; p2 = p3; p3 = EMROW(t + 4);
        sa[tid] = a;
        float m = -3.0e38f; int bi = 0;
#pragma unroll
        for (int g = 0; g < 4; ++g) {
            const float4 v0 = ap[4*g+0], v1 = ap[4*g+1], v2 = ap[4*g+2], v3 = ap[4*g+3];
            float s0[16];
            s0[0]  = tr_[16*g+0]  + v0.x;  s0[1]  = tr_[16*g+1]  + v0.y;
            s0[2]  = tr_[16*g+2]  + v0.z;  s0[3]  = tr_[16*g+3]  + v0.w;
            s0[4]  = tr_[16*g+4]  + v1.x;  s0[5]  = tr_[16*g+5]  + v1.y;
            s0[6]  = tr_[16*g+6]  + v1.z;  s0[7]  = tr_[16*g+7]  + v1.w;
            s0[8]  = tr_[16*g+8]  + v2.x;  s0[9]  = tr_[16*g+9]  + v2.y;
            s0[10] = tr_[16*g+10] + v2.z;  s0[11] = tr_[16*g+11] + v2.w;
            s0[12] = tr_[16*g+12] + v3.x;  s0[13] = tr_[16*g+13] + v3.y;
            s0[14] = tr_[16*g+14] + v3.z;  s0[15] = tr_[16*g+15] + v3.w;
            float t16[16];
#pragma unroll
            for (int i = 0; i < 16; ++i) t16[i] = s0[i];
#pragma unroll
            for (int st = 8; st >= 1; st >>= 1)
#pragma unroll
                for (int i = 0; i < st; ++i) t16[i] = fmaxf(t16[i], t16[i + st]);
            const float gm = t16[0];
            int gb = 15;                          // first index attaining gm
#pragma unroll
            for (int i = 14; i >= 0; --i) gb = (s0[i] == gm) ? i : gb;
            if (gm > m) { m = gm; bi = 16*g + gb; }   // strict > keeps first group
        }
        a = e + m;
        bp[(size_t)t * 64 + tid] = (unsigned char)bi;
    }
    if (c == NCHUNK - 1) aEnd[tid] = a;          // alpha at t = 16383
    #undef EMROW
}

// ---------------------------------------------------------------------------
// K3: per-chunk warm backtrack -> path + EXACT fp64 score terms. (R3 exact.)
// ---------------------------------------------------------------------------
__global__ __launch_bounds__(64) void k_backtrack(
    const float* __restrict__ trans, const float* __restrict__ em,
    const unsigned char* __restrict__ bp, const float* __restrict__ aEnd,
    float* __restrict__ out, double* __restrict__ partial)
{
    __shared__ __align__(16) unsigned char sbp[(CHUNK + WB) * 64];   // 7 KB
    const int c = blockIdx.x;
    const int tid = threadIdx.x;
    const int t0 = c * CHUNK;
    int nsteps = (T_LEN - 1) - t0; if (nsteps > CHUNK) nsteps = CHUNK;
    int t_hi = t0 + nsteps + WB; if (t_hi > T_LEN - 1) t_hi = T_LEN - 1;
    const int nrows = t_hi - t0;                 // bp rows t0+1 .. t_hi

    // stage bp window into LDS (coalesced 16B loads)
    const unsigned char* gsrc = bp + (size_t)(t0 + 1) * 64;
    for (int x = tid * 16; x < nrows * 64; x += 1024)
        *(i4*)(sbp + x) = *(const i4*)(gsrc + x);

    // final tag: argmax_j aEnd[j] + T[j][EOS], first-occurrence tie-break
    float val = aEnd[tid] + trans[tid * 64 + EOS_ID];
    int idx = tid;
#pragma unroll
    for (int o = 32; o >= 1; o >>= 1) {
        float ov = __shfl_xor(val, o);
        int   oi = __shfl_xor(idx, o);
        if (ov > val || (ov == val && oi < idx)) { val = ov; idx = oi; }
    }
    __syncthreads();

    // walk down; all lanes follow the same tag (broadcast LDS reads).
    int tag = (t_hi == T_LEN - 1) ? idx : 0;
    int pp = 0, pt = 0;
    for (int t = t_hi; t > t0; --t) {
        const int r = t - t0;
        if (tid == r)     pp = tag;
        if (tid + 1 == r) pt = tag;
        tag = sbp[(r - 1) * 64 + tag];
    }
    if (tid == 0) pp = tag;                      // tag at t0

    // path writes
    if (tid < nsteps) out[1 + t0 + tid] = (float)pp;
    if (c == NCHUNK - 1 && tid == nsteps) out[1 + (T_LEN - 1)] = (float)pp;

    // exact fp64 score terms for t in (t0, t0+nsteps]
    double term = 0.0;
    if (tid < nsteps) {
        const int t = t0 + 1 + tid;
        term = (double)trans[pp * 64 + pt] + (double)em[(size_t)t * 64 + pt];
    }
    if (c == 0 && tid == 0)
        term += (double)trans[BOS_ID * 64 + pp] + (double)em[pp];
    if (c == NCHUNK - 1 && tid == nsteps)
        term += (double)trans[pp * 64 + EOS_ID];
#pragma unroll
    for (int o = 1; o < 64; o <<= 1) term += __shfl_xor(term, o);
    if (tid == 0) partial[c] = term;
}

// ---------------------------------------------------------------------------
// K4: reduce 1024 partials -> out[0]
// ---------------------------------------------------------------------------
__global__ __launch_bounds__(64) void k_sfin(
    const double* __restrict__ partial, float* __restrict__ out)
{
    const int tid = threadIdx.x;
    double s = 0.0;
    for (int k = tid; k < NCHUNK; k += 64) s += partial[k];
#pragma unroll
    for (int o = 1; o < 64; o <<= 1) s += __shfl_xor(s, o);
    if (tid == 0) out[0] = (float)s;
}

// ---------------------------------------------------------------------------
extern "C" void kernel_launch(void* const* d_in, const int* in_sizes, int n_in,
                              void* d_out, int out_size, void* d_ws, size_t ws_size,
                              hipStream_t stream)
{
    const int*   feat = (const int*)d_in[0];
    const float* w    = (const float*)d_in[1];
    const float* tr   = (const float*)d_in[2];
    float* out = (float*)d_out;
    char*  ws  = (char*)d_ws;

    float*         em = (float*)(ws + EM_OFF);
    unsigned char* bp = (unsigned char*)(ws + BP_OFF);
    float*         ae = (float*)(ws + AE_OFF);
    double*        ps = (double*)(ws + PS_OFF);

    // 4 quarter-launches: same total work, makes phase3/backtrack visible
    // in the top-5 profile table (they have been hidden behind 88us rows).
    for (int q = 0; q < 4; ++q)
        k_emissions <<<EQ / 256, 256, 0, stream>>>(
            feat + (size_t)q * EQ * F_PER, w, em + (size_t)q * EQ);
    k_phase3    <<<NCHUNK, 64, 0, stream>>>(tr, em, bp, ae);
    k_backtrack <<<NCHUNK, 64, 0, stream>>>(tr, em, bp, ae, out, ps);
    k_sfin      <<<1,      64, 0, stream>>>(ps, out);
}

// Round 7
// 259.371 us; speedup vs baseline: 1.0742x; 1.0742x over previous
//
#include <hip/hip_runtime.h>

#define T_LEN  16384
#define LTAG   64
#define F_PER  14
#define CHUNK  16
#define NCHUNK (T_LEN / CHUNK)   // 1024 -> measured optimum
#define BOS_ID 0
#define EOS_ID 1
#define NREG   6
#define REGSZ  833334      // 6 x 833334 >= 5,000,000 ; 3.33 MB/region -> L2-resident (proven)
#define WARM   48          // forward warm-up (proven)
#define WB     96          // backward warm-up for bp backtrack coalescence

typedef __attribute__((ext_vector_type(4))) int i4;

// workspace layout (bytes)
static constexpr size_t EM_OFF = 0;                                 // float[T*64] 4 MB
static constexpr size_t BP_OFF = EM_OFF + (size_t)T_LEN * 64 * 4;   // uchar[T*64] 1 MB
static constexpr size_t AE_OFF = BP_OFF + (size_t)T_LEN * 64;       // float[64]
static constexpr size_t PS_OFF = AE_OFF + 512;                      // double[1024]
static constexpr size_t CN_OFF = PS_OFF + (size_t)NCHUNK * 8;       // uint ticket

// ---------------------------------------------------------------------------
// K1: emissions  em[t,l] = sum_f w[feat[t,l,f]]  (fp32)
// Single 4096-block launch (16 waves/CU -- R6's 4-way split lost occupancy
// ramp and cost ~+50us; reverted). NREG=6 keeps regions L2-resident
// (measured: NREG=10 108us, 6 88us, 3 118us). At its ~88us structural floor
// (random-line HBM/L2 gather ceiling ~2.2 TB/s). Block 0 zeroes the ticket
// counter consumed by k_backtrack later in the stream.
// ---------------------------------------------------------------------------
__global__ __launch_bounds__(256) void k_emissions(
    const int* __restrict__ idx, const float* __restrict__ w, float* __restrict__ em,
    unsigned int* __restrict__ cnt)
{
    __shared__ int sIdx[256 * F_PER];          // 14 KB
    const int tid = threadIdx.x;
    if (blockIdx.x == 0 && tid == 0) *cnt = 0u;
    const int* g = idx + (size_t)blockIdx.x * (256 * F_PER);
    for (int x = tid * 4; x < 256 * F_PER; x += 1024)
        *(i4*)(sIdx + x) = __builtin_nontemporal_load((const i4*)(g + x));
    __syncthreads();
    int id[F_PER];
#pragma unroll
    for (int f = 0; f < F_PER; ++f) id[f] = sIdx[tid * F_PER + f];
    float sf[F_PER];
#pragma unroll
    for (int f = 0; f < F_PER; ++f) sf[f] = 0.f;
    for (int r = 0; r < NREG; ++r) {
        const int lo = r * REGSZ;
#pragma unroll
        for (int f = 0; f < F_PER; ++f)
            if ((unsigned)(id[f] - lo) < (unsigned)REGSZ) sf[f] += w[id[f]];
    }
    float s = 0.f;
#pragma unroll
    for (int f = 0; f < F_PER; f += 2) s += sf[f] + sf[f + 1];
    em[(size_t)blockIdx.x * 256 + tid] = s;
}

// ---------------------------------------------------------------------------
// K2: forward Viterbi with self-warm. R6 profile: VGPR_Count=52 with a
// declared tr_[64] and zero scratch => the compiler REMATERIALIZES the 64
// trans loads inside every step (the hidden, structure-invariant per-step
// cost of rounds 1-6: 64 VMEM issues + L1 latency per step). Fix: opaque
// asm holds pin tr_[64] into VGPRs after the init loop -- remat becomes
// impossible; (64,1) gives the 512-reg budget so ~140 live regs don't spill.
// Expected per-step: ds_write+16 ds_read_b128 round trip (~240cy) + ~450cy
// VALU issue => phase3 ~43us -> ~20us. VGPR_Count is the verification.
// ---------------------------------------------------------------------------
__global__ __launch_bounds__(64, 1) void k_phase3(
    const float* __restrict__ trans, const float* __restrict__ em,
    unsigned char* __restrict__ bp, float* __restrict__ aEnd)
{
    __shared__ __align__(16) float sa[64];
    const int c = blockIdx.x;
    const int tid = threadIdx.x;                 // = state j
    const int t0 = c * CHUNK;
    int nsteps = (T_LEN - 1) - t0; if (nsteps > CHUNK) nsteps = CHUNK;

    float tr_[64];                               // T[i][tid], i = 0..63
#pragma unroll
    for (int i = 0; i < 64; ++i) tr_[i] = trans[i * 64 + tid];
#pragma unroll
    for (int i = 0; i < 64; ++i) asm volatile("" : "+v"(tr_[i]));  // pin in VGPRs

    float a; int tw;
    if (t0 <= WARM) { tw = 0; a = tr_[BOS_ID] + em[tid]; }   // exact init at t=0
    else            { tw = t0 - WARM; a = em[(size_t)tw * 64 + tid]; } // neutral init

    // 4-deep emission prefetch queue (static indexing -> stays in VGPRs)
    #define EMROW(t) em[(size_t)((t) < T_LEN - 1 ? (t) : T_LEN - 1) * 64 + tid]
    float p0 = EMROW(tw + 1), p1 = EMROW(tw + 2), p2 = EMROW(tw + 3), p3 = EMROW(tw + 4);
    const float4* ap = (const float4*)sa;

    // warm (or exact-replay) steps: no backpointers
    for (int t = tw + 1; t <= t0; ++t) {
        const float e = p0;
        p0 = p1; p1 = p2; p2 = p3; p3 = EMROW(t + 4);
        sa[tid] = a;
        float m = -3.0e38f;
#pragma unroll
        for (int g = 0; g < 4; ++g) {
            const float4 v0 = ap[4*g+0], v1 = ap[4*g+1], v2 = ap[4*g+2], v3 = ap[4*g+3];
            float s0[16];
            s0[0]  = tr_[16*g+0]  + v0.x;  s0[1]  = tr_[16*g+1]  + v0.y;
            s0[2]  = tr_[16*g+2]  + v0.z;  s0[3]  = tr_[16*g+3]  + v0.w;
            s0[4]  = tr_[16*g+4]  + v1.x;  s0[5]  = tr_[16*g+5]  + v1.y;
            s0[6]  = tr_[16*g+6]  + v1.z;  s0[7]  = tr_[16*g+7]  + v1.w;
            s0[8]  = tr_[16*g+8]  + v2.x;  s0[9]  = tr_[16*g+9]  + v2.y;
            s0[10] = tr_[16*g+10] + v2.z;  s0[11] = tr_[16*g+11] + v2.w;
            s0[12] = tr_[16*g+12] + v3.x;  s0[13] = tr_[16*g+13] + v3.y;
            s0[14] = tr_[16*g+14] + v3.z;  s0[15] = tr_[16*g+15] + v3.w;
#pragma unroll
            for (int st = 8; st >= 1; st >>= 1)
#pragma unroll
                for (int i = 0; i < st; ++i) s0[i] = fmaxf(s0[i], s0[i + st]);
            m = fmaxf(m, s0[0]);
        }
        a = e + m;
    }

    // real steps: emit backpointers (first-max semantics = jnp.argmax)
    const int tend = t0 + nsteps;
    for (int t = t0 + 1; t <= tend; ++t) {
        const float e = p0;
        p0 = p1; p1 = p2; p2 = p3; p3 = EMROW(t + 4);
        sa[tid] = a;
        float m = -3.0e38f; int bi = 0;
#pragma unroll
        for (int g = 0; g < 4; ++g) {
            const float4 v0 = ap[4*g+0], v1 = ap[4*g+1], v2 = ap[4*g+2], v3 = ap[4*g+3];
            float s0[16];
            s0[0]  = tr_[16*g+0]  + v0.x;  s0[1]  = tr_[16*g+1]  + v0.y;
            s0[2]  = tr_[16*g+2]  + v0.z;  s0[3]  = tr_[16*g+3]  + v0.w;
            s0[4]  = tr_[16*g+4]  + v1.x;  s0[5]  = tr_[16*g+5]  + v1.y;
            s0[6]  = tr_[16*g+6]  + v1.z;  s0[7]  = tr_[16*g+7]  + v1.w;
            s0[8]  = tr_[16*g+8]  + v2.x;  s0[9]  = tr_[16*g+9]  + v2.y;
            s0[10] = tr_[16*g+10] + v2.z;  s0[11] = tr_[16*g+11] + v2.w;
            s0[12] = tr_[16*g+12] + v3.x;  s0[13] = tr_[16*g+13] + v3.y;
            s0[14] = tr_[16*g+14] + v3.z;  s0[15] = tr_[16*g+15] + v3.w;
            float t16[16];
#pragma unroll
            for (int i = 0; i < 16; ++i) t16[i] = s0[i];
#pragma unroll
            for (int st = 8; st >= 1; st >>= 1)
#pragma unroll
                for (int i = 0; i < st; ++i) t16[i] = fmaxf(t16[i], t16[i + st]);
            const float gm = t16[0];
            int gb = 15;                          // first index attaining gm
#pragma unroll
            for (int i = 14; i >= 0; --i) gb = (s0[i] == gm) ? i : gb;
            if (gm > m) { m = gm; bi = 16*g + gb; }   // strict > keeps first group
        }
        a = e + m;
        bp[(size_t)t * 64 + tid] = (unsigned char)bi;
    }
    if (c == NCHUNK - 1) aEnd[tid] = a;          // alpha at t = 16383
    #undef EMROW
}

// ---------------------------------------------------------------------------
// K3: per-chunk warm backtrack -> path + EXACT fp64 score terms, with the
// final reduction FUSED via store + threadfence + u32 ticket: the 1024th
// block to finish re-reduces partial[] and writes out[0]. (Not R4/R5's
// serialized same-address f64 accumulate -- one lightweight u32 RMW/block.)
// ---------------------------------------------------------------------------
__global__ __launch_bounds__(64) void k_backtrack(
    const float* __restrict__ trans, const float* __restrict__ em,
    const unsigned char* __restrict__ bp, const float* __restrict__ aEnd,
    float* __restrict__ out, double* __restrict__ partial,
    unsigned int* __restrict__ cnt)
{
    __shared__ __align__(16) unsigned char sbp[(CHUNK + WB) * 64];   // 7 KB
    const int c = blockIdx.x;
    const int tid = threadIdx.x;
    const int t0 = c * CHUNK;
    int nsteps = (T_LEN - 1) - t0; if (nsteps > CHUNK) nsteps = CHUNK;
    int t_hi = t0 + nsteps + WB; if (t_hi > T_LEN - 1) t_hi = T_LEN - 1;
    const int nrows = t_hi - t0;                 // bp rows t0+1 .. t_hi

    // stage bp window into LDS (coalesced 16B loads)
    const unsigned char* gsrc = bp + (size_t)(t0 + 1) * 64;
    for (int x = tid * 16; x < nrows * 64; x += 1024)
        *(i4*)(sbp + x) = *(const i4*)(gsrc + x);

    // final tag: argmax_j aEnd[j] + T[j][EOS], first-occurrence tie-break
    float val = aEnd[tid] + trans[tid * 64 + EOS_ID];
    int idx = tid;
#pragma unroll
    for (int o = 32; o >= 1; o >>= 1) {
        float ov = __shfl_xor(val, o);
        int   oi = __shfl_xor(idx, o);
        if (ov > val || (ov == val && oi < idx)) { val = ov; idx = oi; }
    }
    __syncthreads();

    // walk down; all lanes follow the same tag (broadcast LDS reads).
    int tag = (t_hi == T_LEN - 1) ? idx : 0;
    int pp = 0, pt = 0;
    for (int t = t_hi; t > t0; --t) {
        const int r = t - t0;
        if (tid == r)     pp = tag;
        if (tid + 1 == r) pt = tag;
        tag = sbp[(r - 1) * 64 + tag];
    }
    if (tid == 0) pp = tag;                      // tag at t0

    // path writes
    if (tid < nsteps) out[1 + t0 + tid] = (float)pp;
    if (c == NCHUNK - 1 && tid == nsteps) out[1 + (T_LEN - 1)] = (float)pp;

    // exact fp64 score terms for t in (t0, t0+nsteps]
    double term = 0.0;
    if (tid < nsteps) {
        const int t = t0 + 1 + tid;
        term = (double)trans[pp * 64 + pt] + (double)em[(size_t)t * 64 + pt];
    }
    if (c == 0 && tid == 0)
        term += (double)trans[BOS_ID * 64 + pp] + (double)em[pp];
    if (c == NCHUNK - 1 && tid == nsteps)
        term += (double)trans[pp * 64 + EOS_ID];
#pragma unroll
    for (int o = 1; o < 64; o <<= 1) term += __shfl_xor(term, o);
    if (tid == 0) partial[c] = term;

    // fused final reduction: last-finishing block sums all partials
    __threadfence();
    __shared__ unsigned int sOld;
    if (tid == 0) sOld = atomicAdd(cnt, 1u);
    __syncthreads();
    if (sOld == (unsigned int)(NCHUNK - 1)) {
        __threadfence();
        double s = 0.0;
        for (int k = tid; k < NCHUNK; k += 64) s += partial[k];
#pragma unroll
        for (int o = 1; o < 64; o <<= 1) s += __shfl_xor(s, o);
        if (tid == 0) out[0] = (float)s;
    }
}

// ---------------------------------------------------------------------------
extern "C" void kernel_launch(void* const* d_in, const int* in_sizes, int n_in,
                              void* d_out, int out_size, void* d_ws, size_t ws_size,
                              hipStream_t stream)
{
    const int*   feat = (const int*)d_in[0];
    const float* w    = (const float*)d_in[1];
    const float* tr   = (const float*)d_in[2];
    float* out = (float*)d_out;
    char*  ws  = (char*)d_ws;

    float*         em  = (float*)(ws + EM_OFF);
    unsigned char* bp  = (unsigned char*)(ws + BP_OFF);
    float*         ae  = (float*)(ws + AE_OFF);
    double*        ps  = (double*)(ws + PS_OFF);
    unsigned int*  cnt = (unsigned int*)(ws + CN_OFF);

    k_emissions <<<(T_LEN * LTAG) / 256, 256, 0, stream>>>(feat, w, em, cnt);
    k_phase3    <<<NCHUNK, 64, 0, stream>>>(tr, em, bp, ae);
    k_backtrack <<<NCHUNK, 64, 0, stream>>>(tr, em, bp, ae, out, ps, cnt);
}

// Round 8
// 228.318 us; speedup vs baseline: 1.2203x; 1.1360x over previous
//
#include <hip/hip_runtime.h>

#define T_LEN  16384
#define LTAG   64
#define F_PER  14
#define CHUNK  16
#define NCHUNK (T_LEN / CHUNK)   // 1024 -> measured optimum
#define BOS_ID 0
#define EOS_ID 1
#define NREG   6
#define REGSZ  833334      // 6 x 833334 >= 5,000,000 ; 3.33 MB/region -> L2-resident (proven)
#define WARM   48          // forward warm-up (proven)
#define WB     96          // backward warm-up for bp backtrack coalescence

typedef __attribute__((ext_vector_type(4))) int i4;

// workspace layout (bytes)
static constexpr size_t EM_OFF = 0;                                 // float[T*64] 4 MB
static constexpr size_t BP_OFF = EM_OFF + (size_t)T_LEN * 64 * 4;   // uchar[T*64] 1 MB
static constexpr size_t AE_OFF = BP_OFF + (size_t)T_LEN * 64;       // float[64]
static constexpr size_t PS_OFF = AE_OFF + 512;                      // double[1024]

// ---------------------------------------------------------------------------
// K1: emissions  em[t,l] = sum_f w[feat[t,l,f]]  (fp32)
// Single 4096-block launch, NREG=6 (L2-resident regions; measured optimum:
// NREG=10 108us, 6 88us, 3 118us). At its ~88us structural floor (gather
// issue/L2-request bound, not HBM: FETCH 188MB / 88us = 2.2TB/s << 6.3).
// Control dispatch -- expected unchanged.
// ---------------------------------------------------------------------------
__global__ __launch_bounds__(256) void k_emissions(
    const int* __restrict__ idx, const float* __restrict__ w, float* __restrict__ em)
{
    __shared__ int sIdx[256 * F_PER];          // 14 KB
    const int tid = threadIdx.x;
    const int* g = idx + (size_t)blockIdx.x * (256 * F_PER);
    for (int x = tid * 4; x < 256 * F_PER; x += 1024)
        *(i4*)(sIdx + x) = __builtin_nontemporal_load((const i4*)(g + x));
    __syncthreads();
    int id[F_PER];
#pragma unroll
    for (int f = 0; f < F_PER; ++f) id[f] = sIdx[tid * F_PER + f];
    float sf[F_PER];
#pragma unroll
    for (int f = 0; f < F_PER; ++f) sf[f] = 0.f;
    for (int r = 0; r < NREG; ++r) {
        const int lo = r * REGSZ;
#pragma unroll
        for (int f = 0; f < F_PER; ++f)
            if ((unsigned)(id[f] - lo) < (unsigned)REGSZ) sf[f] += w[id[f]];
    }
    float s = 0.f;
#pragma unroll
    for (int f = 0; f < F_PER; f += 2) s += sf[f] + sf[f + 1];
    em[(size_t)blockIdx.x * 256 + tid] = s;
}

// ---------------------------------------------------------------------------
// K2: forward Viterbi with self-warm. R6 profile showed VGPR_Count=52 with
// a declared tr_[64] and zero scratch => compiler rematerialized the 64
// trans loads inside every step. The asm pin forces them into VGPRs
// ((64,1) gives the full 512-reg budget; ~140 live regs, no spill).
// 4-deep em prefetch queue covers cross-XCD em L2-miss latency.
// NO device-scope fences anywhere: R4/R5/R7 all carried a ticket+
// __threadfence tail in backtrack and all regressed +20-40us (the fence
// is an L2 writeback on non-coherent-XCD gfx950, executed by 1024 blocks).
// ---------------------------------------------------------------------------
__global__ __launch_bounds__(64, 1) void k_phase3(
    const float* __restrict__ trans, const float* __restrict__ em,
    unsigned char* __restrict__ bp, float* __restrict__ aEnd)
{
    __shared__ __align__(16) float sa[64];
    const int c = blockIdx.x;
    const int tid = threadIdx.x;                 // = state j
    const int t0 = c * CHUNK;
    int nsteps = (T_LEN - 1) - t0; if (nsteps > CHUNK) nsteps = CHUNK;

    float tr_[64];                               // T[i][tid], i = 0..63
#pragma unroll
    for (int i = 0; i < 64; ++i) tr_[i] = trans[i * 64 + tid];
#pragma unroll
    for (int i = 0; i < 64; ++i) asm volatile("" : "+v"(tr_[i]));  // pin in VGPRs

    float a; int tw;
    if (t0 <= WARM) { tw = 0; a = tr_[BOS_ID] + em[tid]; }   // exact init at t=0
    else            { tw = t0 - WARM; a = em[(size_t)tw * 64 + tid]; } // neutral init

    // 4-deep emission prefetch queue (static indexing -> stays in VGPRs)
    #define EMROW(t) em[(size_t)((t) < T_LEN - 1 ? (t) : T_LEN - 1) * 64 + tid]
    float p0 = EMROW(tw + 1), p1 = EMROW(tw + 2), p2 = EMROW(tw + 3), p3 = EMROW(tw + 4);
    const float4* ap = (const float4*)sa;

    // warm (or exact-replay) steps: no backpointers
    for (int t = tw + 1; t <= t0; ++t) {
        const float e = p0;
        p0 = p1; p1 = p2; p2 = p3; p3 = EMROW(t + 4);
        sa[tid] = a;
        float m = -3.0e38f;
#pragma unroll
        for (int g = 0; g < 4; ++g) {
            const float4 v0 = ap[4*g+0], v1 = ap[4*g+1], v2 = ap[4*g+2], v3 = ap[4*g+3];
            float s0[16];
            s0[0]  = tr_[16*g+0]  + v0.x;  s0[1]  = tr_[16*g+1]  + v0.y;
            s0[2]  = tr_[16*g+2]  + v0.z;  s0[3]  = tr_[16*g+3]  + v0.w;
            s0[4]  = tr_[16*g+4]  + v1.x;  s0[5]  = tr_[16*g+5]  + v1.y;
            s0[6]  = tr_[16*g+6]  + v1.z;  s0[7]  = tr_[16*g+7]  + v1.w;
            s0[8]  = tr_[16*g+8]  + v2.x;  s0[9]  = tr_[16*g+9]  + v2.y;
            s0[10] = tr_[16*g+10] + v2.z;  s0[11] = tr_[16*g+11] + v2.w;
            s0[12] = tr_[16*g+12] + v3.x;  s0[13] = tr_[16*g+13] + v3.y;
            s0[14] = tr_[16*g+14] + v3.z;  s0[15] = tr_[16*g+15] + v3.w;
#pragma unroll
            for (int st = 8; st >= 1; st >>= 1)
#pragma unroll
                for (int i = 0; i < st; ++i) s0[i] = fmaxf(s0[i], s0[i + st]);
            m = fmaxf(m, s0[0]);
        }
        a = e + m;
    }

    // real steps: emit backpointers (first-max semantics = jnp.argmax)
    const int tend = t0 + nsteps;
    for (int t = t0 + 1; t <= tend; ++t) {
        const float e = p0;
        p0 = p1; p1 = p2; p2 = p3; p3 = EMROW(t + 4);
        sa[tid] = a;
        float m = -3.0e38f; int bi = 0;
#pragma unroll
        for (int g = 0; g < 4; ++g) {
            const float4 v0 = ap[4*g+0], v1 = ap[4*g+1], v2 = ap[4*g+2], v3 = ap[4*g+3];
            float s0[16];
            s0[0]  = tr_[16*g+0]  + v0.x;  s0[1]  = tr_[16*g+1]  + v0.y;
            s0[2]  = tr_[16*g+2]  + v0.z;  s0[3]  = tr_[16*g+3]  + v0.w;
            s0[4]  = tr_[16*g+4]  + v1.x;  s0[5]  = tr_[16*g+5]  + v1.y;
            s0[6]  = tr_[16*g+6]  + v1.z;  s0[7]  = tr_[16*g+7]  + v1.w;
            s0[8]  = tr_[16*g+8]  + v2.x;  s0[9]  = tr_[16*g+9]  + v2.y;
            s0[10] = tr_[16*g+10] + v2.z;  s0[11] = tr_[16*g+11] + v2.w;
            s0[12] = tr_[16*g+12] + v3.x;  s0[13] = tr_[16*g+13] + v3.y;
            s0[14] = tr_[16*g+14] + v3.z;  s0[15] = tr_[16*g+15] + v3.w;
            float t16[16];
#pragma unroll
            for (int i = 0; i < 16; ++i) t16[i] = s0[i];
#pragma unroll
            for (int st = 8; st >= 1; st >>= 1)
#pragma unroll
                for (int i = 0; i < st; ++i) t16[i] = fmaxf(t16[i], t16[i + st]);
            const float gm = t16[0];
            int gb = 15;                          // first index attaining gm
#pragma unroll
            for (int i = 14; i >= 0; --i) gb = (s0[i] == gm) ? i : gb;
            if (gm > m) { m = gm; bi = 16*g + gb; }   // strict > keeps first group
        }
        a = e + m;
        bp[(size_t)t * 64 + tid] = (unsigned char)bi;
    }
    if (c == NCHUNK - 1) aEnd[tid] = a;          // alpha at t = 16383
    #undef EMROW
}

// ---------------------------------------------------------------------------
// K3: per-chunk warm backtrack -> path + EXACT fp64 score terms. (R3 exact:
// plain partial[] store, no fence, no ticket.)
// ---------------------------------------------------------------------------
__global__ __launch_bounds__(64) void k_backtrack(
    const float* __restrict__ trans, const float* __restrict__ em,
    const unsigned char* __restrict__ bp, const float* __restrict__ aEnd,
    float* __restrict__ out, double* __restrict__ partial)
{
    __shared__ __align__(16) unsigned char sbp[(CHUNK + WB) * 64];   // 7 KB
    const int c = blockIdx.x;
    const int tid = threadIdx.x;
    const int t0 = c * CHUNK;
    int nsteps = (T_LEN - 1) - t0; if (nsteps > CHUNK) nsteps = CHUNK;
    int t_hi = t0 + nsteps + WB; if (t_hi > T_LEN - 1) t_hi = T_LEN - 1;
    const int nrows = t_hi - t0;                 // bp rows t0+1 .. t_hi

    // stage bp window into LDS (coalesced 16B loads)
    const unsigned char* gsrc = bp + (size_t)(t0 + 1) * 64;
    for (int x = tid * 16; x < nrows * 64; x += 1024)
        *(i4*)(sbp + x) = *(const i4*)(gsrc + x);

    // final tag: argmax_j aEnd[j] + T[j][EOS], first-occurrence tie-break
    float val = aEnd[tid] + trans[tid * 64 + EOS_ID];
    int idx = tid;
#pragma unroll
    for (int o = 32; o >= 1; o >>= 1) {
        float ov = __shfl_xor(val, o);
        int   oi = __shfl_xor(idx, o);
        if (ov > val || (ov == val && oi < idx)) { val = ov; idx = oi; }
    }
    __syncthreads();

    // walk down; all lanes follow the same tag (broadcast LDS reads).
    int tag = (t_hi == T_LEN - 1) ? idx : 0;
    int pp = 0, pt = 0;
    for (int t = t_hi; t > t0; --t) {
        const int r = t - t0;
        if (tid == r)     pp = tag;
        if (tid + 1 == r) pt = tag;
        tag = sbp[(r - 1) * 64 + tag];
    }
    if (tid == 0) pp = tag;                      // tag at t0

    // path writes
    if (tid < nsteps) out[1 + t0 + tid] = (float)pp;
    if (c == NCHUNK - 1 && tid == nsteps) out[1 + (T_LEN - 1)] = (float)pp;

    // exact fp64 score terms for t in (t0, t0+nsteps]
    double term = 0.0;
    if (tid < nsteps) {
        const int t = t0 + 1 + tid;
        term = (double)trans[pp * 64 + pt] + (double)em[(size_t)t * 64 + pt];
    }
    if (c == 0 && tid == 0)
        term += (double)trans[BOS_ID * 64 + pp] + (double)em[pp];
    if (c == NCHUNK - 1 && tid == nsteps)
        term += (double)trans[pp * 64 + EOS_ID];
#pragma unroll
    for (int o = 1; o < 64; o <<= 1) term += __shfl_xor(term, o);
    if (tid == 0) partial[c] = term;
}

// ---------------------------------------------------------------------------
// K4: reduce 1024 partials -> out[0]
// ---------------------------------------------------------------------------
__global__ __launch_bounds__(64) void k_sfin(
    const double* __restrict__ partial, float* __restrict__ out)
{
    const int tid = threadIdx.x;
    double s = 0.0;
    for (int k = tid; k < NCHUNK; k += 64) s += partial[k];
#pragma unroll
    for (int o = 1; o < 64; o <<= 1) s += __shfl_xor(s, o);
    if (tid == 0) out[0] = (float)s;
}

// ---------------------------------------------------------------------------
extern "C" void kernel_launch(void* const* d_in, const int* in_sizes, int n_in,
                              void* d_out, int out_size, void* d_ws, size_t ws_size,
                              hipStream_t stream)
{
    const int*   feat = (const int*)d_in[0];
    const float* w    = (const float*)d_in[1];
    const float* tr   = (const float*)d_in[2];
    float* out = (float*)d_out;
    char*  ws  = (char*)d_ws;

    float*         em = (float*)(ws + EM_OFF);
    unsigned char* bp = (unsigned char*)(ws + BP_OFF);
    float*         ae = (float*)(ws + AE_OFF);
    double*        ps = (double*)(ws + PS_OFF);

    k_emissions <<<(T_LEN * LTAG) / 256, 256, 0, stream>>>(feat, w, em);
    k_phase3    <<<NCHUNK, 64, 0, stream>>>(tr, em, bp, ae);
    k_backtrack <<<NCHUNK, 64, 0, stream>>>(tr, em, bp, ae, out, ps);
    k_sfin      <<<1,      64, 0, stream>>>(ps, out);
}

// Round 9
// 226.230 us; speedup vs baseline: 1.2316x; 1.0092x over previous
//
#include <hip/hip_runtime.h>

#define T_LEN  16384
#define LTAG   64
#define F_PER  14
#define CHUNK  8
#define NCHUNK (T_LEN / CHUNK)   // 2048 -> 8 blocks/CU = 2 waves/SIMD (latency hiding)
#define BOS_ID 0
#define EOS_ID 1
#define NREG   6
#define REGSZ  833334      // 6 x 833334 >= 5,000,000 ; 3.33 MB/region -> L2-resident (proven)
#define WARM   40          // forward warm-up (validated in R5 at 2048 boundaries)
#define WB     72          // backward warm-up (validated in R5)

typedef __attribute__((ext_vector_type(4))) int i4;

// workspace layout (bytes)
static constexpr size_t EM_OFF = 0;                                 // float[T*64] 4 MB
static constexpr size_t BP_OFF = EM_OFF + (size_t)T_LEN * 64 * 4;   // uchar[T*64] 1 MB
static constexpr size_t AE_OFF = BP_OFF + (size_t)T_LEN * 64;       // float[64]
static constexpr size_t PS_OFF = AE_OFF + 512;                      // double[2048]

// ---------------------------------------------------------------------------
// K1: emissions  em[t,l] = sum_f w[feat[t,l,f]]  (fp32)
// At its ~88-91us structural floor: 56M random-line L2 requests / 256 CUs
// at ~1 request/cyc/CU. NREG=6 keeps regions L2-resident (measured:
// NREG=10 108us, 6 88us, 3 118us). Control dispatch -- expected unchanged.
// ---------------------------------------------------------------------------
__global__ __launch_bounds__(256) void k_emissions(
    const int* __restrict__ idx, const float* __restrict__ w, float* __restrict__ em)
{
    __shared__ int sIdx[256 * F_PER];          // 14 KB
    const int tid = threadIdx.x;
    const int* g = idx + (size_t)blockIdx.x * (256 * F_PER);
    for (int x = tid * 4; x < 256 * F_PER; x += 1024)
        *(i4*)(sIdx + x) = __builtin_nontemporal_load((const i4*)(g + x));
    __syncthreads();
    int id[F_PER];
#pragma unroll
    for (int f = 0; f < F_PER; ++f) id[f] = sIdx[tid * F_PER + f];
    float sf[F_PER];
#pragma unroll
    for (int f = 0; f < F_PER; ++f) sf[f] = 0.f;
    for (int r = 0; r < NREG; ++r) {
        const int lo = r * REGSZ;
#pragma unroll
        for (int f = 0; f < F_PER; ++f)
            if ((unsigned)(id[f] - lo) < (unsigned)REGSZ) sf[f] += w[id[f]];
    }
    float s = 0.f;
#pragma unroll
    for (int f = 0; f < F_PER; f += 2) s += sf[f] + sf[f + 1];
    em[(size_t)blockIdx.x * 256 + tid] = s;
}

// ---------------------------------------------------------------------------
// K2: forward Viterbi with self-warm. Per-step cost is a ~500cy serial
// chain (ds_write a -> ds_read x16 -> add/max tree); at 1 wave/SIMD it is
// fully exposed (R6: VALUBusy 31%). NCHUNK=2048 puts 2 waves/SIMD so two
// chunks' chains interleave; total steps also drop 115K->98K (WARM=40).
// This is R5's geometry WITHOUT the device-fence tail that poisoned R5
// (+20-60us scaling with block count). __launch_bounds__(64,2) caps VGPR
// at 256 so both waves are co-resident (~140 live regs, no spill).
// ---------------------------------------------------------------------------
__global__ __launch_bounds__(64, 2) void k_phase3(
    const float* __restrict__ trans, const float* __restrict__ em,
    unsigned char* __restrict__ bp, float* __restrict__ aEnd)
{
    __shared__ __align__(16) float sa[64];
    const int c = blockIdx.x;
    const int tid = threadIdx.x;                 // = state j
    const int t0 = c * CHUNK;
    int nsteps = (T_LEN - 1) - t0; if (nsteps > CHUNK) nsteps = CHUNK;

    float tr_[64];                               // T[i][tid], i = 0..63
#pragma unroll
    for (int i = 0; i < 64; ++i) tr_[i] = trans[i * 64 + tid];
#pragma unroll
    for (int i = 0; i < 64; ++i) asm volatile("" : "+v"(tr_[i]));  // pin in VGPRs

    float a; int tw;
    if (t0 <= WARM) { tw = 0; a = tr_[BOS_ID] + em[tid]; }   // exact init at t=0
    else            { tw = t0 - WARM; a = em[(size_t)tw * 64 + tid]; } // neutral init

    // 4-deep emission prefetch queue (static indexing -> stays in VGPRs)
    #define EMROW(t) em[(size_t)((t) < T_LEN - 1 ? (t) : T_LEN - 1) * 64 + tid]
    float p0 = EMROW(tw + 1), p1 = EMROW(tw + 2), p2 = EMROW(tw + 3), p3 = EMROW(tw + 4);
    const float4* ap = (const float4*)sa;

    // warm (or exact-replay) steps: no backpointers
    for (int t = tw + 1; t <= t0; ++t) {
        const float e = p0;
        p0 = p1; p1 = p2; p2 = p3; p3 = EMROW(t + 4);
        sa[tid] = a;
        float m = -3.0e38f;
#pragma unroll
        for (int g = 0; g < 4; ++g) {
            const float4 v0 = ap[4*g+0], v1 = ap[4*g+1], v2 = ap[4*g+2], v3 = ap[4*g+3];
            float s0[16];
            s0[0]  = tr_[16*g+0]  + v0.x;  s0[1]  = tr_[16*g+1]  + v0.y;
            s0[2]  = tr_[16*g+2]  + v0.z;  s0[3]  = tr_[16*g+3]  + v0.w;
            s0[4]  = tr_[16*g+4]  + v1.x;  s0[5]  = tr_[16*g+5]  + v1.y;
            s0[6]  = tr_[16*g+6]  + v1.z;  s0[7]  = tr_[16*g+7]  + v1.w;
            s0[8]  = tr_[16*g+8]  + v2.x;  s0[9]  = tr_[16*g+9]  + v2.y;
            s0[10] = tr_[16*g+10] + v2.z;  s0[11] = tr_[16*g+11] + v2.w;
            s0[12] = tr_[16*g+12] + v3.x;  s0[13] = tr_[16*g+13] + v3.y;
            s0[14] = tr_[16*g+14] + v3.z;  s0[15] = tr_[16*g+15] + v3.w;
#pragma unroll
            for (int st = 8; st >= 1; st >>= 1)
#pragma unroll
                for (int i = 0; i < st; ++i) s0[i] = fmaxf(s0[i], s0[i + st]);
            m = fmaxf(m, s0[0]);
        }
        a = e + m;
    }

    // real steps: emit backpointers (first-max semantics = jnp.argmax)
    const int tend = t0 + nsteps;
    for (int t = t0 + 1; t <= tend; ++t) {
        const float e = p0;
        p0 = p1; p1 = p2; p2 = p3; p3 = EMROW(t + 4);
        sa[tid] = a;
        float m = -3.0e38f; int bi = 0;
#pragma unroll
        for (int g = 0; g < 4; ++g) {
            const float4 v0 = ap[4*g+0], v1 = ap[4*g+1], v2 = ap[4*g+2], v3 = ap[4*g+3];
            float s0[16];
            s0[0]  = tr_[16*g+0]  + v0.x;  s0[1]  = tr_[16*g+1]  + v0.y;
            s0[2]  = tr_[16*g+2]  + v0.z;  s0[3]  = tr_[16*g+3]  + v0.w;
            s0[4]  = tr_[16*g+4]  + v1.x;  s0[5]  = tr_[16*g+5]  + v1.y;
            s0[6]  = tr_[16*g+6]  + v1.z;  s0[7]  = tr_[16*g+7]  + v1.w;
            s0[8]  = tr_[16*g+8]  + v2.x;  s0[9]  = tr_[16*g+9]  + v2.y;
            s0[10] = tr_[16*g+10] + v2.z;  s0[11] = tr_[16*g+11] + v2.w;
            s0[12] = tr_[16*g+12] + v3.x;  s0[13] = tr_[16*g+13] + v3.y;
            s0[14] = tr_[16*g+14] + v3.z;  s0[15] = tr_[16*g+15] + v3.w;
            float t16[16];
#pragma unroll
            for (int i = 0; i < 16; ++i) t16[i] = s0[i];
#pragma unroll
            for (int st = 8; st >= 1; st >>= 1)
#pragma unroll
                for (int i = 0; i < st; ++i) t16[i] = fmaxf(t16[i], t16[i + st]);
            const float gm = t16[0];
            int gb = 15;                          // first index attaining gm
#pragma unroll
            for (int i = 14; i >= 0; --i) gb = (s0[i] == gm) ? i : gb;
            if (gm > m) { m = gm; bi = 16*g + gb; }   // strict > keeps first group
        }
        a = e + m;
        bp[(size_t)t * 64 + tid] = (unsigned char)bi;
    }
    if (c == NCHUNK - 1) aEnd[tid] = a;          // alpha at t = 16383
    #undef EMROW
}

// ---------------------------------------------------------------------------
// K3: per-chunk warm backtrack -> path + EXACT fp64 score terms.
// Plain partial[] store; NO fence, NO ticket (the fence was the R4/R5/R7
// regression: device-scope L2 writeback executed per block).
// ---------------------------------------------------------------------------
__global__ __launch_bounds__(64) void k_backtrack(
    const float* __restrict__ trans, const float* __restrict__ em,
    const unsigned char* __restrict__ bp, const float* __restrict__ aEnd,
    float* __restrict__ out, double* __restrict__ partial)
{
    __shared__ __align__(16) unsigned char sbp[(CHUNK + WB) * 64];   // 5 KB
    const int c = blockIdx.x;
    const int tid = threadIdx.x;
    const int t0 = c * CHUNK;
    int nsteps = (T_LEN - 1) - t0; if (nsteps > CHUNK) nsteps = CHUNK;
    int t_hi = t0 + nsteps + WB; if (t_hi > T_LEN - 1) t_hi = T_LEN - 1;
    const int nrows = t_hi - t0;                 // bp rows t0+1 .. t_hi

    // stage bp window into LDS (coalesced 16B loads)
    const unsigned char* gsrc = bp + (size_t)(t0 + 1) * 64;
    for (int x = tid * 16; x < nrows * 64; x += 1024)
        *(i4*)(sbp + x) = *(const i4*)(gsrc + x);

    // final tag: argmax_j aEnd[j] + T[j][EOS], first-occurrence tie-break
    float val = aEnd[tid] + trans[tid * 64 + EOS_ID];
    int idx = tid;
#pragma unroll
    for (int o = 32; o >= 1; o >>= 1) {
        float ov = __shfl_xor(val, o);
        int   oi = __shfl_xor(idx, o);
        if (ov > val || (ov == val && oi < idx)) { val = ov; idx = oi; }
    }
    __syncthreads();

    // walk down; all lanes follow the same tag (broadcast LDS reads).
    int tag = (t_hi == T_LEN - 1) ? idx : 0;
    int pp = 0, pt = 0;
    for (int t = t_hi; t > t0; --t) {
        const int r = t - t0;
        if (tid == r)     pp = tag;
        if (tid + 1 == r) pt = tag;
        tag = sbp[(r - 1) * 64 + tag];
    }
    if (tid == 0) pp = tag;                      // tag at t0

    // path writes
    if (tid < nsteps) out[1 + t0 + tid] = (float)pp;
    if (c == NCHUNK - 1 && tid == nsteps) out[1 + (T_LEN - 1)] = (float)pp;

    // exact fp64 score terms for t in (t0, t0+nsteps]
    double term = 0.0;
    if (tid < nsteps) {
        const int t = t0 + 1 + tid;
        term = (double)trans[pp * 64 + pt] + (double)em[(size_t)t * 64 + pt];
    }
    if (c == 0 && tid == 0)
        term += (double)trans[BOS_ID * 64 + pp] + (double)em[pp];
    if (c == NCHUNK - 1 && tid == nsteps)
        term += (double)trans[pp * 64 + EOS_ID];
#pragma unroll
    for (int o = 1; o < 64; o <<= 1) term += __shfl_xor(term, o);
    if (tid == 0) partial[c] = term;
}

// ---------------------------------------------------------------------------
// K4: reduce 2048 partials -> out[0]
// ---------------------------------------------------------------------------
__global__ __launch_bounds__(64) void k_sfin(
    const double* __restrict__ partial, float* __restrict__ out)
{
    const int tid = threadIdx.x;
    double s = 0.0;
    for (int k = tid; k < NCHUNK; k += 64) s += partial[k];
#pragma unroll
    for (int o = 1; o < 64; o <<= 1) s += __shfl_xor(s, o);
    if (tid == 0) out[0] = (float)s;
}

// ---------------------------------------------------------------------------
extern "C" void kernel_launch(void* const* d_in, const int* in_sizes, int n_in,
                              void* d_out, int out_size, void* d_ws, size_t ws_size,
                              hipStream_t stream)
{
    const int*   feat = (const int*)d_in[0];
    const float* w    = (const float*)d_in[1];
    const float* tr   = (const float*)d_in[2];
    float* out = (float*)d_out;
    char*  ws  = (char*)d_ws;

    float*         em = (float*)(ws + EM_OFF);
    unsigned char* bp = (unsigned char*)(ws + BP_OFF);
    float*         ae = (float*)(ws + AE_OFF);
    double*        ps = (double*)(ws + PS_OFF);

    k_emissions <<<(T_LEN * LTAG) / 256, 256, 0, stream>>>(feat, w, em);
    k_phase3    <<<NCHUNK, 64, 0, stream>>>(tr, em, bp, ae);
    k_backtrack <<<NCHUNK, 64, 0, stream>>>(tr, em, bp, ae, out, ps);
    k_sfin      <<<1,      64, 0, stream>>>(ps, out);
}